// Round 7
// baseline (820.398 us; speedup 1.0000x reference)
//
#include <hip/hip_runtime.h>
#include <math.h>

#define Bsz 128
#define Tsz 256
#define Isz 256
#define Hsz 256
#define Lsz 4
#define Ssz 3
#define Mrows (Bsz*Tsz)   // 32768

using f16x8 = __attribute__((ext_vector_type(8))) _Float16;
using f32x4 = __attribute__((ext_vector_type(4))) float;

__device__ inline float fast_sig(float x) { return 1.f / (1.f + __expf(-x)); }
__device__ inline float fast_tanh(float x) {
  const float e = __expf(-2.f * fabsf(x));
  const float y = (1.f - e) / (1.f + e);
  return x < 0.f ? -y : y;
}

// ---------------- fp32 -> fp16 convert ----------------
__global__ __launch_bounds__(256) void f32_to_f16(
    const float* __restrict__ src, _Float16* __restrict__ dst, int n8)
{
  const int idx = blockIdx.x * 256 + threadIdx.x;
  if (idx >= n8) return;
  const float4 v0 = *(const float4*)(src + (size_t)idx * 8);
  const float4 v1 = *(const float4*)(src + (size_t)idx * 8 + 4);
  _Float16 h[8];
  h[0] = (_Float16)v0.x; h[1] = (_Float16)v0.y;
  h[2] = (_Float16)v0.z; h[3] = (_Float16)v0.w;
  h[4] = (_Float16)v1.x; h[5] = (_Float16)v1.y;
  h[6] = (_Float16)v1.z; h[7] = (_Float16)v1.w;
  *(uint4*)(dst + (size_t)idx * 8) = *(uint4*)h;
}

// ---------------- fused GRU-layer GEMM + ep partial dots ----------------
// Round-4-proven single-buffer K-loop; epilogue: gating -> LDS transpose ->
// coalesced b128 h stores + fused e/p partial dot products (atomicAdd).
// grid: (M/128, 256/64, 3 cur). block 256 = 4 waves.
__global__ __launch_bounds__(256, 3) void gemm_gru_f16(
    const _Float16* __restrict__ Abase, size_t a_cur_stride,
    const _Float16* __restrict__ Wbase, size_t w_cur_stride,
    const float* __restrict__ bi_g, size_t bi_stride,
    const float* __restrict__ bh_g, size_t bh_stride,
    _Float16* __restrict__ Hout,
    const float* __restrict__ w_lw, const float* __restrict__ w_sel,
    float* __restrict__ e, float* __restrict__ p, int layer)
{
  // SB: A staging [0,4160) chunk-major (ch*130+row)*8; W staging [4160,10496)
  // epilogue reuses SB[0,10240) as 128x64 transpose area (stride 80 fp16)
  __shared__ __attribute__((aligned(16))) _Float16 SB[10496];   // 20992 B
  __shared__ float w7[7][64];                                    // 1792 B
  __shared__ float ps[2][128][7];                                // 7168 B
  _Float16* const AhS = SB;
  _Float16* const WhS = SB + 4160;

  const int tid = threadIdx.x;
  const int cu  = blockIdx.z;
  const int m0  = blockIdx.x * 128;
  const int n0  = blockIdx.y * 64;

  const _Float16* A = Abase + (size_t)cu * a_cur_stride;
  const _Float16* W = Wbase + (size_t)cu * w_cur_stride;
  const float* bi = bi_g + (size_t)cu * bi_stride;
  const float* bh = bh_g + (size_t)cu * bh_stride;

  const int lane = tid & 63;
  const int wv   = tid >> 6;
  const int q    = lane >> 4;      // k-chunk within frag
  const int c    = lane & 15;      // row/col within frag
  const int mb   = wv * 32;        // wave's row base within 128-tile

  // stage the 7x64 ep weight slice (read only in epilogue)
  for (int u = tid; u < 448; u += 256) {
    const int j = u >> 6, i = u & 63;
    w7[j][i] = (j < 4) ? w_lw[j * 256 + n0 + i] : w_sel[(j - 4) * 512 + n0 + i];
  }

  f32x4 acc[3][2][4];
  #pragma unroll
  for (int s = 0; s < 3; s++)
    #pragma unroll
    for (int mi = 0; mi < 2; mi++)
      #pragma unroll
      for (int ni = 0; ni < 4; ni++)
        acc[s][mi][ni] = (f32x4)0.f;

  for (int k0 = 0; k0 < 256; k0 += 32) {
    // stage A tile (128 x 32)
    #pragma unroll
    for (int i = 0; i < 2; i++) {
      const int idx = tid + i * 256;        // 0..511
      const int row = idx >> 2, ch = idx & 3;
      *(uint4*)&AhS[(ch * 130 + row) * 8] =
          *(const uint4*)(A + (size_t)(m0 + row) * 256 + k0 + ch * 8);
    }
    // stage W tiles (3 slabs x 64 x 32)
    #pragma unroll
    for (int i = 0; i < 3; i++) {
      const int idx = tid + i * 256;        // 0..767
      const int s = idx >> 8, rr = (idx >> 2) & 63, ch = idx & 3;
      *(uint4*)&WhS[((s * 4 + ch) * 66 + rr) * 8] =
          *(const uint4*)(W + (size_t)(s * 256 + n0 + rr) * 256 + k0 + ch * 8);
    }
    __syncthreads();

    const f16x8 a0 = *(const f16x8*)&AhS[(q * 130 + mb + c) * 8];
    const f16x8 a1 = *(const f16x8*)&AhS[(q * 130 + mb + 16 + c) * 8];

    #pragma unroll
    for (int s = 0; s < 3; s++) {
      #pragma unroll
      for (int ni = 0; ni < 4; ni++) {
        const f16x8 w = *(const f16x8*)&WhS[((s * 4 + q) * 66 + ni * 16 + c) * 8];
        acc[s][0][ni] = __builtin_amdgcn_mfma_f32_16x16x32_f16(a0, w, acc[s][0][ni], 0, 0, 0);
        acc[s][1][ni] = __builtin_amdgcn_mfma_f32_16x16x32_f16(a1, w, acc[s][1][ni], 0, 0, 0);
      }
    }
    __syncthreads();
  }

  // ---- epilogue: gating ----
  float bir[4], biz[4], bin_[4], bhr[4], bhz[4], bhn[4];
  #pragma unroll
  for (int ni = 0; ni < 4; ni++) {
    const int n = n0 + ni * 16 + c;
    bir[ni]  = bi[n];       bhr[ni] = bh[n];
    biz[ni]  = bi[256 + n]; bhz[ni] = bh[256 + n];
    bin_[ni] = bi[512 + n]; bhn[ni] = bh[512 + n];
  }
  _Float16 hv[2][4][4];   // [mi][reg][ni]
  #pragma unroll
  for (int mi = 0; mi < 2; mi++)
    #pragma unroll
    for (int reg = 0; reg < 4; reg++)
      #pragma unroll
      for (int ni = 0; ni < 4; ni++) {
        const float gr = acc[0][mi][ni][reg] + bir[ni] + bhr[ni];
        const float gz = acc[1][mi][ni][reg] + biz[ni] + bhz[ni];
        const float gn = acc[2][mi][ni][reg] + bin_[ni];
        const float r  = fast_sig(gr);
        const float zz = fast_sig(gz);
        const float nn = fast_tanh(gn + r * bhn[ni]);
        hv[mi][reg][ni] = (_Float16)((1.f - zz) * nn);
      }
  __syncthreads();   // staging reads done; reuse SB as transpose area
  // transpose: [m][n], stride 80 fp16 (160 B -> 16B-aligned)
  #pragma unroll
  for (int mi = 0; mi < 2; mi++)
    #pragma unroll
    for (int reg = 0; reg < 4; reg++) {
      const int m = mb + mi * 16 + q * 4 + reg;
      #pragma unroll
      for (int ni = 0; ni < 4; ni++)
        SB[m * 80 + ni * 16 + c] = hv[mi][reg][ni];
    }
  __syncthreads();
  // coalesced h store + fused ep partial dots
  {
    const int r = tid >> 1, part = tid & 1;     // 2 threads/row, 32 fp16 each
    const size_t gb = ((size_t)cu * Mrows + m0 + r) * 256 + n0 + part * 32;
    const _Float16* src = &SB[r * 80 + part * 32];
    float pd[7] = {0.f, 0.f, 0.f, 0.f, 0.f, 0.f, 0.f};
    #pragma unroll
    for (int i = 0; i < 4; i++) {
      union { uint4 u; _Float16 h[8]; } cv;
      cv.u = *(const uint4*)(src + i * 8);
      *(uint4*)(Hout + gb + i * 8) = cv.u;
      #pragma unroll
      for (int k = 0; k < 8; k++) {
        const float hf = (float)cv.h[k];
        const int n = part * 32 + i * 8 + k;
        #pragma unroll
        for (int j = 0; j < 7; j++) pd[j] += hf * w7[j][n];
      }
    }
    #pragma unroll
    for (int j = 0; j < 7; j++) ps[part][r][j] = pd[j];
  }
  __syncthreads();
  if (tid < 128) {
    float d[7];
    #pragma unroll
    for (int j = 0; j < 7; j++) d[j] = ps[0][tid][j] + ps[1][tid][j];
    const int mrow = m0 + tid;
    const int b = mrow >> 8, t = mrow & 255;    // mrow = b*T + t
    const size_t base = ((size_t)cu * Tsz + t) * Bsz + b;
    #pragma unroll
    for (int j = 0; j < 4; j++) atomicAdd(&e[base * 16 + layer * 4 + j], d[j]);
    #pragma unroll
    for (int j = 0; j < 3; j++) atomicAdd(&p[base * 12 + layer * 3 + j], d[4 + j]);
  }
}

// ---------------- softmax-attention + batch-reduced selector scores ----------------
__global__ __launch_bounds__(128) void attn_finish(
    const float* __restrict__ e, const float* __restrict__ p,
    const float* __restrict__ hidden, const float* __restrict__ b_lw,
    float* __restrict__ score_h)
{
  const int t = blockIdx.x, cc = blockIdx.y;
  const int b = threadIdx.x;
  const float* eb = e + ((size_t)(cc * Tsz + t) * Bsz + b) * 16;
  const float* pb = p + ((size_t)(cc * Tsz + t) * Bsz + b) * 12;
  const float* hb = hidden + b * 16;
  const float bl0 = b_lw[0], bl1 = b_lw[1], bl2 = b_lw[2], bl3 = b_lw[3];
  float attn[4];
  #pragma unroll
  for (int i = 0; i < 4; i++) {
    attn[i] = hb[i * 4 + 0] * (eb[i * 4 + 0] + bl0)
            + hb[i * 4 + 1] * (eb[i * 4 + 1] + bl1)
            + hb[i * 4 + 2] * (eb[i * 4 + 2] + bl2)
            + hb[i * 4 + 3] * (eb[i * 4 + 3] + bl3);
  }
  const float mx = fmaxf(fmaxf(attn[0], attn[1]), fmaxf(attn[2], attn[3]));
  float ex[4], sum = 0.f;
  #pragma unroll
  for (int i = 0; i < 4; i++) { ex[i] = expf(attn[i] - mx); sum += ex[i]; }
  const float inv = 1.f / sum;
  float sc[3];
  #pragma unroll
  for (int s = 0; s < 3; s++) {
    float v = 0.f;
    #pragma unroll
    for (int i = 0; i < 4; i++) v += ex[i] * pb[i * 3 + s];
    sc[s] = v * inv;
  }
  #pragma unroll
  for (int off = 32; off; off >>= 1)
    #pragma unroll
    for (int s = 0; s < 3; s++) sc[s] += __shfl_xor(sc[s], off);
  __shared__ float red[2][3];
  const int wv = threadIdx.x >> 6, ln = threadIdx.x & 63;
  if (ln == 0) { red[wv][0] = sc[0]; red[wv][1] = sc[1]; red[wv][2] = sc[2]; }
  __syncthreads();
  if (threadIdx.x == 0) {
    #pragma unroll
    for (int s = 0; s < 3; s++)
      score_h[((size_t)cc * Tsz + t) * 3 + s] = red[0][s] + red[1][s];
  }
}

// ---------------- xs[t,s] ----------------
__global__ __launch_bounds__(256) void xs_kernel(
    const float* __restrict__ x, const float* __restrict__ w_sel,
    const float* __restrict__ b_sel, float* __restrict__ xs)
{
  const int t = blockIdx.x, k = threadIdx.x;
  float s = 0.f;
  for (int b = 0; b < Bsz; b++) s += x[((size_t)b * Tsz + t) * Isz + k];
  float pr[3];
  #pragma unroll
  for (int qq = 0; qq < 3; qq++) pr[qq] = s * w_sel[qq * (Hsz + Isz) + Hsz + k];
  #pragma unroll
  for (int off = 32; off; off >>= 1)
    #pragma unroll
    for (int qq = 0; qq < 3; qq++) pr[qq] += __shfl_xor(pr[qq], off);
  __shared__ float red[4][3];
  const int wv = k >> 6, ln = k & 63;
  if (ln == 0) { red[wv][0] = pr[0]; red[wv][1] = pr[1]; red[wv][2] = pr[2]; }
  __syncthreads();
  if (k == 0) {
    #pragma unroll
    for (int qq = 0; qq < 3; qq++)
      xs[t * 3 + qq] = red[0][qq] + red[1][qq] + red[2][qq] + red[3][qq]
                      + (float)Bsz * b_sel[qq];
  }
}

// ---------------- selector chain via parallel scan (composition is associative) ----------------
__global__ __launch_bounds__(256) void select_kernel(
    const float* __restrict__ score_h, const float* __restrict__ xs,
    int* __restrict__ cur)
{
  __shared__ unsigned char g[2][Tsz][3];
  const int t = threadIdx.x;
  // g[0][0] = identity; g[0][t>=1] = f[t] (transition table)
  if (t == 0) {
    g[0][0][0] = 0; g[0][0][1] = 1; g[0][0][2] = 2;
  } else {
    const float* xr = xs + t * 3;
    #pragma unroll
    for (int cc = 0; cc < 3; cc++) {
      const float* sh = score_h + ((size_t)cc * Tsz + (t - 1)) * 3;
      const float v0 = sh[0] + xr[0];
      const float v1 = sh[1] + xr[1];
      const float v2 = sh[2] + xr[2];
      int best = 0; float bv = v0;
      if (v1 > bv) { bv = v1; best = 1; }
      if (v2 > bv) { bv = v2; best = 2; }
      g[0][t][cc] = (unsigned char)best;
    }
  }
  __syncthreads();
  int src = 0;
  for (int off = 1; off < Tsz; off <<= 1) {
    const int dst = src ^ 1;
    if (t >= off) {
      #pragma unroll
      for (int s = 0; s < 3; s++)
        g[dst][t][s] = g[src][t][g[src][t - off][s]];
    } else {
      #pragma unroll
      for (int s = 0; s < 3; s++) g[dst][t][s] = g[src][t][s];
    }
    __syncthreads();
    src = dst;
  }
  cur[t] = (int)g[src][t][0];
}

// ---------------- gather outputs (fp16 h -> fp32 out) ----------------
__global__ __launch_bounds__(256) void gather_out(
    const _Float16* __restrict__ Hh, const int* __restrict__ cur,
    float* __restrict__ out)
{
  const size_t idx = ((size_t)blockIdx.x * 256 + threadIdx.x) * 4;
  const size_t BTH = (size_t)Bsz * Tsz * Hsz;
  int b, t, h;
  if (idx < BTH) {
    b = (int)(idx >> 16);
    const int rem = (int)(idx & 65535);
    t = rem >> 8; h = rem & 255;
  } else {
    const size_t r2 = idx - BTH;
    b = (int)(r2 >> 8); h = (int)(r2 & 255); t = Tsz - 1;
  }
  const int cc = cur[t];
  const size_t g = (((size_t)cc * Mrows + (size_t)b * Tsz + t) * Hsz + h);
  union { ushort4 u; _Float16 hv[4]; } cv;
  cv.u = *(const ushort4*)(Hh + g);
  float4 v;
  v.x = (float)cv.hv[0]; v.y = (float)cv.hv[1];
  v.z = (float)cv.hv[2]; v.w = (float)cv.hv[3];
  *(float4*)(out + idx) = v;
}

extern "C" void kernel_launch(void* const* d_in, const int* in_sizes, int n_in,
                              void* d_out, int out_size, void* d_ws, size_t ws_size,
                              hipStream_t stream) {
  const float* x      = (const float*)d_in[0];
  const float* hidden = (const float*)d_in[1];
  const float* w_ih0  = (const float*)d_in[2];
  const float* b_ih0  = (const float*)d_in[3];
  const float* b_hh0  = (const float*)d_in[4];
  const float* w_ih   = (const float*)d_in[5];
  const float* b_ih   = (const float*)d_in[6];
  const float* b_hh   = (const float*)d_in[7];
  const float* w_lw   = (const float*)d_in[8];
  const float* b_lw   = (const float*)d_in[9];
  const float* w_sel  = (const float*)d_in[10];
  const float* b_sel  = (const float*)d_in[11];
  float* out = (float*)d_out;

  char* w = (char*)d_ws;
  const size_t HN = (size_t)3 * Mrows * 256;       // 25.2M
  const size_t XN = (size_t)Bsz * Tsz * Isz;       // 8.39M
  const size_t W0N = (size_t)3 * 768 * 256;        // 589824
  const size_t WLN = (size_t)3 * 3 * 768 * 256;    // 1769472
  _Float16* HA  = (_Float16*)w; w += HN * 2;
  _Float16* HB  = (_Float16*)w; w += HN * 2;
  _Float16* xh  = (_Float16*)w; w += XN * 2;
  _Float16* Wh0 = (_Float16*)w; w += W0N * 2;
  _Float16* WhL = (_Float16*)w; w += WLN * 2;
  const size_t EN = (size_t)3 * Tsz * Bsz * 16;    // e floats
  const size_t PN = (size_t)3 * Tsz * Bsz * 12;    // p floats
  float* e       = (float*)w; w += EN * 4;
  float* p       = (float*)w; w += PN * 4;
  float* score_h = (float*)w; w += (size_t)3 * Tsz * 3 * 4;
  float* xsb     = (float*)w; w += (size_t)Tsz * 3 * 4;
  int*   curb    = (int*)w;   w += (size_t)Tsz * 4;

  // fp32 -> fp16 conversions
  f32_to_f16<<<(int)(XN / 8 + 255) / 256, 256, 0, stream>>>(x, xh, (int)(XN / 8));
  f32_to_f16<<<(int)(W0N / 8 + 255) / 256, 256, 0, stream>>>(w_ih0, Wh0, (int)(W0N / 8));
  f32_to_f16<<<(int)(WLN / 8 + 255) / 256, 256, 0, stream>>>(w_ih, WhL, (int)(WLN / 8));
  // zero e/p accumulators (atomics add into them)
  hipMemsetAsync(e, 0, EN * 4, stream);
  hipMemsetAsync(p, 0, PN * 4, stream);

  dim3 ggrid(Mrows / 128, 4, 3);

  // layer 0: A = xh (shared across cur)
  gemm_gru_f16<<<ggrid, 256, 0, stream>>>(
      xh, (size_t)0, Wh0, (size_t)768 * 256,
      b_ih0, (size_t)768, b_hh0, (size_t)768, HA,
      w_lw, w_sel, e, p, 0);

  const size_t wcur = (size_t)3 * 768 * 256;
  const size_t bst  = (size_t)3 * 768;
  _Float16* ping = HA; _Float16* pong = HB;
  for (int l = 1; l < 4; l++) {
    gemm_gru_f16<<<ggrid, 256, 0, stream>>>(
        ping, (size_t)Mrows * 256,
        WhL + (size_t)(l - 1) * 768 * 256, wcur,
        b_ih + (size_t)(l - 1) * 768, bst,
        b_hh + (size_t)(l - 1) * 768, bst, pong,
        w_lw, w_sel, e, p, l);
    _Float16* t1 = ping; ping = pong; pong = t1;
  }

  attn_finish<<<dim3(Tsz, 3), 128, 0, stream>>>(e, p, hidden, b_lw, score_h);
  xs_kernel<<<Tsz, 256, 0, stream>>>(x, w_sel, b_sel, xsb);
  select_kernel<<<1, 256, 0, stream>>>(score_h, xsb, curb);
  gather_out<<<8224, 256, 0, stream>>>(ping, curb, out);
}

// Round 8
// 587.572 us; speedup vs baseline: 1.3963x; 1.3963x over previous
//
#include <hip/hip_runtime.h>
#include <math.h>

#define Bsz 128
#define Tsz 256
#define Isz 256
#define Hsz 256
#define Lsz 4
#define Ssz 3
#define Mrows (Bsz*Tsz)   // 32768

using f16x8 = __attribute__((ext_vector_type(8))) _Float16;
using f32x4 = __attribute__((ext_vector_type(4))) float;

__device__ inline float fast_sig(float x) { return 1.f / (1.f + __expf(-x)); }
__device__ inline float fast_tanh(float x) {
  const float e = __expf(-2.f * fabsf(x));
  const float y = (1.f - e) / (1.f + e);
  return x < 0.f ? -y : y;
}

// ---------------- fp32 -> fp16 convert (weights) ----------------
__global__ __launch_bounds__(256) void f32_to_f16(
    const float* __restrict__ src, _Float16* __restrict__ dst, int n8)
{
  const int idx = blockIdx.x * 256 + threadIdx.x;
  if (idx >= n8) return;
  const float4 v0 = *(const float4*)(src + (size_t)idx * 8);
  const float4 v1 = *(const float4*)(src + (size_t)idx * 8 + 4);
  _Float16 h[8];
  h[0] = (_Float16)v0.x; h[1] = (_Float16)v0.y;
  h[2] = (_Float16)v0.z; h[3] = (_Float16)v0.w;
  h[4] = (_Float16)v1.x; h[5] = (_Float16)v1.y;
  h[6] = (_Float16)v1.z; h[7] = (_Float16)v1.w;
  *(uint4*)(dst + (size_t)idx * 8) = *(uint4*)h;
}

// ---------------- fused GRU-layer GEMM, fp16 MFMA ----------------
// Round-4 single-buffer K-loop; wave tile 64m x 32n x 3slabs (W-frag reuse:
// 10 ds_read_b128 per 24 MFMAs instead of 14). Epilogue: gating -> LDS
// transpose (stride 80) -> coalesced b128 stores.
// grid: (M/128, 256/64, 3 cur). block 256 = 4 waves (2 along m x 2 along n).
template<bool AF32>
__global__ __launch_bounds__(256, 3) void gemm_gru_f16(
    const float* __restrict__ Af,
    const _Float16* __restrict__ Ah_g, size_t a_cur_stride,
    const _Float16* __restrict__ Wbase, size_t w_cur_stride,
    const float* __restrict__ bi_g, size_t bi_stride,
    const float* __restrict__ bh_g, size_t bh_stride,
    _Float16* __restrict__ Hout)
{
  // SB: staging A [0,4160) chunk-major, W [4160,10496); epilogue reuses
  // [0,10240) as 128x64 transpose area (stride 80 fp16, 16B-aligned rows)
  __shared__ __attribute__((aligned(16))) _Float16 SB[10496];   // 20992 B
  _Float16* const AhS = SB;
  _Float16* const WhS = SB + 4160;

  const int tid = threadIdx.x;
  const int cu  = blockIdx.z;
  const int m0  = blockIdx.x * 128;
  const int n0  = blockIdx.y * 64;

  const _Float16* A = AF32 ? nullptr : (Ah_g + (size_t)cu * a_cur_stride);
  const _Float16* W = Wbase + (size_t)cu * w_cur_stride;
  const float* bi = bi_g + (size_t)cu * bi_stride;
  const float* bh = bh_g + (size_t)cu * bh_stride;

  const int lane = tid & 63;
  const int wv   = tid >> 6;
  const int q    = lane >> 4;          // k-chunk within frag
  const int c    = lane & 15;          // row/col within frag
  const int mwv  = (wv & 1) * 64;      // wave m base within 128-tile
  const int nwv  = (wv >> 1) * 32;     // wave n base within 64-tile

  f32x4 acc[3][4][2];                  // [slab][mi][ni]
  #pragma unroll
  for (int s = 0; s < 3; s++)
    #pragma unroll
    for (int mi = 0; mi < 4; mi++)
      #pragma unroll
      for (int ni = 0; ni < 2; ni++)
        acc[s][mi][ni] = (f32x4)0.f;

  for (int k0 = 0; k0 < 256; k0 += 32) {
    // stage A tile (128 x 32)
    #pragma unroll
    for (int i = 0; i < 2; i++) {
      const int idx = tid + i * 256;        // 0..511
      const int row = idx >> 2, ch = idx & 3;
      if (AF32) {
        const float* ag = Af + (size_t)(m0 + row) * 256 + k0 + ch * 8;
        const float4 v0 = *(const float4*)ag;
        const float4 v1 = *(const float4*)(ag + 4);
        _Float16 hh[8];
        hh[0] = (_Float16)v0.x; hh[1] = (_Float16)v0.y;
        hh[2] = (_Float16)v0.z; hh[3] = (_Float16)v0.w;
        hh[4] = (_Float16)v1.x; hh[5] = (_Float16)v1.y;
        hh[6] = (_Float16)v1.z; hh[7] = (_Float16)v1.w;
        *(uint4*)&AhS[(ch * 130 + row) * 8] = *(uint4*)hh;
      } else {
        *(uint4*)&AhS[(ch * 130 + row) * 8] =
            *(const uint4*)(A + (size_t)(m0 + row) * 256 + k0 + ch * 8);
      }
    }
    // stage W tiles (3 slabs x 64 x 32)
    #pragma unroll
    for (int i = 0; i < 3; i++) {
      const int idx = tid + i * 256;        // 0..767
      const int s = idx >> 8, rr = (idx >> 2) & 63, ch = idx & 3;
      *(uint4*)&WhS[((s * 4 + ch) * 66 + rr) * 8] =
          *(const uint4*)(W + (size_t)(s * 256 + n0 + rr) * 256 + k0 + ch * 8);
    }
    __syncthreads();

    f16x8 a[4];
    #pragma unroll
    for (int mi = 0; mi < 4; mi++)
      a[mi] = *(const f16x8*)&AhS[(q * 130 + mwv + mi * 16 + c) * 8];

    #pragma unroll
    for (int s = 0; s < 3; s++) {
      #pragma unroll
      for (int ni = 0; ni < 2; ni++) {
        const f16x8 w = *(const f16x8*)&WhS[((s * 4 + q) * 66 + nwv + ni * 16 + c) * 8];
        #pragma unroll
        for (int mi = 0; mi < 4; mi++)
          acc[s][mi][ni] = __builtin_amdgcn_mfma_f32_16x16x32_f16(a[mi], w, acc[s][mi][ni], 0, 0, 0);
      }
    }
    __syncthreads();
  }

  // ---- epilogue: gating ----
  float bir[2], biz[2], bin_[2], bhr[2], bhz[2], bhn[2];
  #pragma unroll
  for (int ni = 0; ni < 2; ni++) {
    const int n = n0 + nwv + ni * 16 + c;
    bir[ni]  = bi[n];       bhr[ni] = bh[n];
    biz[ni]  = bi[256 + n]; bhz[ni] = bh[256 + n];
    bin_[ni] = bi[512 + n]; bhn[ni] = bh[512 + n];
  }
  _Float16 hv[4][4][2];   // [mi][reg][ni]
  #pragma unroll
  for (int mi = 0; mi < 4; mi++)
    #pragma unroll
    for (int reg = 0; reg < 4; reg++)
      #pragma unroll
      for (int ni = 0; ni < 2; ni++) {
        const float gr = acc[0][mi][ni][reg] + bir[ni] + bhr[ni];
        const float gz = acc[1][mi][ni][reg] + biz[ni] + bhz[ni];
        const float gn = acc[2][mi][ni][reg] + bin_[ni];
        const float r  = fast_sig(gr);
        const float zz = fast_sig(gz);
        const float nn = fast_tanh(gn + r * bhn[ni]);
        hv[mi][reg][ni] = (_Float16)((1.f - zz) * nn);
      }
  // loop-end barrier already separates last LDS frag reads; write transpose
  #pragma unroll
  for (int mi = 0; mi < 4; mi++)
    #pragma unroll
    for (int reg = 0; reg < 4; reg++) {
      const int m = mwv + mi * 16 + q * 4 + reg;
      #pragma unroll
      for (int ni = 0; ni < 2; ni++)
        SB[m * 80 + nwv + ni * 16 + c] = hv[mi][reg][ni];
    }
  __syncthreads();
  {
    const int r = tid >> 1, part = tid & 1;     // 2 threads/row, 32 fp16 each
    const size_t gb = ((size_t)cu * Mrows + m0 + r) * 256 + n0 + part * 32;
    const _Float16* src = &SB[r * 80 + part * 32];
    #pragma unroll
    for (int i = 0; i < 4; i++)
      *(uint4*)(Hout + gb + i * 8) = *(const uint4*)(src + i * 8);
  }
}

// ---------------- per-layer dot products (e, p), block-tiled ----------------
__global__ __launch_bounds__(256) void ep_tile(
    const _Float16* __restrict__ Hh,
    const float* __restrict__ w_lw, const float* __restrict__ w_sel, int layer,
    float* __restrict__ e, float* __restrict__ p)
{
  __shared__ _Float16 hs[64 * 264];
  __shared__ float wc[7][256];
  __shared__ float ps[4][64][8];
  const int tid = threadIdx.x;
  const size_t mg0 = (size_t)blockIdx.x * 64;

  #pragma unroll
  for (int i = 0; i < 8; i++) {
    const int ci = tid + i * 256;
    const int row = ci >> 5, kc = ci & 31;
    *(uint4*)&hs[row * 264 + kc * 8] =
        *(const uint4*)(Hh + (mg0 + row) * 256 + kc * 8);
  }
  #pragma unroll
  for (int j = 0; j < 7; j++)
    wc[j][tid] = (j < 4) ? w_lw[j * 256 + tid] : w_sel[(j - 4) * 512 + tid];
  __syncthreads();

  const int r = tid & 63, pp = tid >> 6;
  float acc[7] = {0.f, 0.f, 0.f, 0.f, 0.f, 0.f, 0.f};
  #pragma unroll
  for (int i = 0; i < 8; i++) {
    union { uint4 u; _Float16 h[8]; } hvv;
    hvv.u = *(uint4*)&hs[r * 264 + pp * 64 + i * 8];
    float hf[8];
    #pragma unroll
    for (int k = 0; k < 8; k++) hf[k] = (float)hvv.h[k];
    #pragma unroll
    for (int j = 0; j < 7; j++) {
      const float4 w0 = *(const float4*)&wc[j][pp * 64 + i * 8];
      const float4 w1 = *(const float4*)&wc[j][pp * 64 + i * 8 + 4];
      acc[j] += hf[0] * w0.x + hf[1] * w0.y + hf[2] * w0.z + hf[3] * w0.w
              + hf[4] * w1.x + hf[5] * w1.y + hf[6] * w1.z + hf[7] * w1.w;
    }
  }
  #pragma unroll
  for (int j = 0; j < 7; j++) ps[pp][r][j] = acc[j];
  __syncthreads();

  if (tid < 64) {
    float d[7];
    #pragma unroll
    for (int j = 0; j < 7; j++)
      d[j] = ps[0][tid][j] + ps[1][tid][j] + ps[2][tid][j] + ps[3][tid][j];
    const size_t mg = mg0 + tid;
    const int cc = (int)(mg >> 15);
    const int m  = (int)(mg & 32767);
    const int b = m >> 8, t = m & 255;
    const size_t base = ((size_t)cc * Tsz + t) * Bsz + b;
    #pragma unroll
    for (int j = 0; j < 4; j++) e[base * 16 + layer * 4 + j] = d[j];
    #pragma unroll
    for (int j = 0; j < 3; j++) p[base * 12 + layer * 3 + j] = d[4 + j];
  }
}

// ---------------- softmax-attention + batch-reduced selector scores ----------------
__global__ __launch_bounds__(128) void attn_finish(
    const float* __restrict__ e, const float* __restrict__ p,
    const float* __restrict__ hidden, const float* __restrict__ b_lw,
    float* __restrict__ score_h)
{
  const int t = blockIdx.x, cc = blockIdx.y;
  const int b = threadIdx.x;
  const float* eb = e + ((size_t)(cc * Tsz + t) * Bsz + b) * 16;
  const float* pb = p + ((size_t)(cc * Tsz + t) * Bsz + b) * 12;
  const float* hb = hidden + b * 16;
  const float bl0 = b_lw[0], bl1 = b_lw[1], bl2 = b_lw[2], bl3 = b_lw[3];
  float attn[4];
  #pragma unroll
  for (int i = 0; i < 4; i++) {
    attn[i] = hb[i * 4 + 0] * (eb[i * 4 + 0] + bl0)
            + hb[i * 4 + 1] * (eb[i * 4 + 1] + bl1)
            + hb[i * 4 + 2] * (eb[i * 4 + 2] + bl2)
            + hb[i * 4 + 3] * (eb[i * 4 + 3] + bl3);
  }
  const float mx = fmaxf(fmaxf(attn[0], attn[1]), fmaxf(attn[2], attn[3]));
  float ex[4], sum = 0.f;
  #pragma unroll
  for (int i = 0; i < 4; i++) { ex[i] = expf(attn[i] - mx); sum += ex[i]; }
  const float inv = 1.f / sum;
  float sc[3];
  #pragma unroll
  for (int s = 0; s < 3; s++) {
    float v = 0.f;
    #pragma unroll
    for (int i = 0; i < 4; i++) v += ex[i] * pb[i * 3 + s];
    sc[s] = v * inv;
  }
  #pragma unroll
  for (int off = 32; off; off >>= 1)
    #pragma unroll
    for (int s = 0; s < 3; s++) sc[s] += __shfl_xor(sc[s], off);
  __shared__ float red[2][3];
  const int wv = threadIdx.x >> 6, ln = threadIdx.x & 63;
  if (ln == 0) { red[wv][0] = sc[0]; red[wv][1] = sc[1]; red[wv][2] = sc[2]; }
  __syncthreads();
  if (threadIdx.x == 0) {
    #pragma unroll
    for (int s = 0; s < 3; s++)
      score_h[((size_t)cc * Tsz + t) * 3 + s] = red[0][s] + red[1][s];
  }
}

// ---------------- xs[t,s] ----------------
__global__ __launch_bounds__(256) void xs_kernel(
    const float* __restrict__ x, const float* __restrict__ w_sel,
    const float* __restrict__ b_sel, float* __restrict__ xs)
{
  const int t = blockIdx.x, k = threadIdx.x;
  float s = 0.f;
  for (int b = 0; b < Bsz; b++) s += x[((size_t)b * Tsz + t) * Isz + k];
  float pr[3];
  #pragma unroll
  for (int qq = 0; qq < 3; qq++) pr[qq] = s * w_sel[qq * (Hsz + Isz) + Hsz + k];
  #pragma unroll
  for (int off = 32; off; off >>= 1)
    #pragma unroll
    for (int qq = 0; qq < 3; qq++) pr[qq] += __shfl_xor(pr[qq], off);
  __shared__ float red[4][3];
  const int wv = k >> 6, ln = k & 63;
  if (ln == 0) { red[wv][0] = pr[0]; red[wv][1] = pr[1]; red[wv][2] = pr[2]; }
  __syncthreads();
  if (k == 0) {
    #pragma unroll
    for (int qq = 0; qq < 3; qq++)
      xs[t * 3 + qq] = red[0][qq] + red[1][qq] + red[2][qq] + red[3][qq]
                      + (float)Bsz * b_sel[qq];
  }
}

// ---------------- selector chain via parallel scan ----------------
__global__ __launch_bounds__(256) void select_kernel(
    const float* __restrict__ score_h, const float* __restrict__ xs,
    int* __restrict__ cur)
{
  __shared__ unsigned char g[2][Tsz][3];
  const int t = threadIdx.x;
  if (t == 0) {
    g[0][0][0] = 0; g[0][0][1] = 1; g[0][0][2] = 2;
  } else {
    const float* xr = xs + t * 3;
    #pragma unroll
    for (int cc = 0; cc < 3; cc++) {
      const float* sh = score_h + ((size_t)cc * Tsz + (t - 1)) * 3;
      const float v0 = sh[0] + xr[0];
      const float v1 = sh[1] + xr[1];
      const float v2 = sh[2] + xr[2];
      int best = 0; float bv = v0;
      if (v1 > bv) { bv = v1; best = 1; }
      if (v2 > bv) { bv = v2; best = 2; }
      g[0][t][cc] = (unsigned char)best;
    }
  }
  __syncthreads();
  int src = 0;
  for (int off = 1; off < Tsz; off <<= 1) {
    const int dst = src ^ 1;
    if (t >= off) {
      #pragma unroll
      for (int s = 0; s < 3; s++)
        g[dst][t][s] = g[src][t][g[src][t - off][s]];
    } else {
      #pragma unroll
      for (int s = 0; s < 3; s++) g[dst][t][s] = g[src][t][s];
    }
    __syncthreads();
    src = dst;
  }
  cur[t] = (int)g[src][t][0];
}

// ---------------- gather outputs (fp16 h -> fp32 out) ----------------
__global__ __launch_bounds__(256) void gather_out(
    const _Float16* __restrict__ Hh, const int* __restrict__ cur,
    float* __restrict__ out)
{
  const size_t idx = ((size_t)blockIdx.x * 256 + threadIdx.x) * 4;
  const size_t BTH = (size_t)Bsz * Tsz * Hsz;
  int b, t, h;
  if (idx < BTH) {
    b = (int)(idx >> 16);
    const int rem = (int)(idx & 65535);
    t = rem >> 8; h = rem & 255;
  } else {
    const size_t r2 = idx - BTH;
    b = (int)(r2 >> 8); h = (int)(r2 & 255); t = Tsz - 1;
  }
  const int cc = cur[t];
  const size_t g = (((size_t)cc * Mrows + (size_t)b * Tsz + t) * Hsz + h);
  union { ushort4 u; _Float16 hv[4]; } cv;
  cv.u = *(const ushort4*)(Hh + g);
  float4 v;
  v.x = (float)cv.hv[0]; v.y = (float)cv.hv[1];
  v.z = (float)cv.hv[2]; v.w = (float)cv.hv[3];
  *(float4*)(out + idx) = v;
}

extern "C" void kernel_launch(void* const* d_in, const int* in_sizes, int n_in,
                              void* d_out, int out_size, void* d_ws, size_t ws_size,
                              hipStream_t stream) {
  const float* x      = (const float*)d_in[0];
  const float* hidden = (const float*)d_in[1];
  const float* w_ih0  = (const float*)d_in[2];
  const float* b_ih0  = (const float*)d_in[3];
  const float* b_hh0  = (const float*)d_in[4];
  const float* w_ih   = (const float*)d_in[5];
  const float* b_ih   = (const float*)d_in[6];
  const float* b_hh   = (const float*)d_in[7];
  const float* w_lw   = (const float*)d_in[8];
  const float* b_lw   = (const float*)d_in[9];
  const float* w_sel  = (const float*)d_in[10];
  const float* b_sel  = (const float*)d_in[11];
  float* out = (float*)d_out;

  char* w = (char*)d_ws;
  const size_t HN = (size_t)3 * Mrows * 256;       // 25.2M
  const size_t W0N = (size_t)3 * 768 * 256;        // 589824
  const size_t WLN = (size_t)3 * 3 * 768 * 256;    // 1769472
  _Float16* HA  = (_Float16*)w; w += HN * 2;
  _Float16* HB  = (_Float16*)w; w += HN * 2;
  _Float16* Wh0 = (_Float16*)w; w += W0N * 2;
  _Float16* WhL = (_Float16*)w; w += WLN * 2;
  float* e       = (float*)w; w += (size_t)3 * Tsz * Bsz * 16 * 4;
  float* p       = (float*)w; w += (size_t)3 * Tsz * Bsz * 12 * 4;
  float* score_h = (float*)w; w += (size_t)3 * Tsz * 3 * 4;
  float* xsb     = (float*)w; w += (size_t)Tsz * 3 * 4;
  int*   curb    = (int*)w;   w += (size_t)Tsz * 4;

  // fp32 -> fp16 weight conversions
  f32_to_f16<<<(int)(W0N / 8 + 255) / 256, 256, 0, stream>>>(w_ih0, Wh0, (int)(W0N / 8));
  f32_to_f16<<<(int)(WLN / 8 + 255) / 256, 256, 0, stream>>>(w_ih, WhL, (int)(WLN / 8));

  dim3 ggrid(Mrows / 128, 4, 3);

  // layer 0: A = x (fp32, converted in-kernel, shared across cur)
  gemm_gru_f16<true><<<ggrid, 256, 0, stream>>>(
      x, nullptr, (size_t)0, Wh0, (size_t)768 * 256,
      b_ih0, (size_t)768, b_hh0, (size_t)768, HA);
  ep_tile<<<(3 * Mrows) / 64, 256, 0, stream>>>(HA, w_lw, w_sel, 0, e, p);

  const size_t wcur = (size_t)3 * 768 * 256;
  const size_t bst  = (size_t)3 * 768;
  _Float16* ping = HA; _Float16* pong = HB;
  for (int l = 1; l < 4; l++) {
    gemm_gru_f16<false><<<ggrid, 256, 0, stream>>>(
        nullptr, ping, (size_t)Mrows * 256,
        WhL + (size_t)(l - 1) * 768 * 256, wcur,
        b_ih + (size_t)(l - 1) * 768, bst,
        b_hh + (size_t)(l - 1) * 768, bst, pong);
    ep_tile<<<(3 * Mrows) / 64, 256, 0, stream>>>(pong, w_lw, w_sel, l, e, p);
    _Float16* t1 = ping; ping = pong; pong = t1;
  }

  attn_finish<<<dim3(Tsz, 3), 128, 0, stream>>>(e, p, hidden, b_lw, score_h);
  xs_kernel<<<Tsz, 256, 0, stream>>>(x, w_sel, b_sel, xsb);
  select_kernel<<<1, 256, 0, stream>>>(score_h, xsb, curb);
  gather_out<<<8224, 256, 0, stream>>>(ping, curb, out);
}

// Round 9
// 581.103 us; speedup vs baseline: 1.4118x; 1.0111x over previous
//
#include <hip/hip_runtime.h>
#include <math.h>

#define Bsz 128
#define Tsz 256
#define Isz 256
#define Hsz 256
#define Lsz 4
#define Ssz 3
#define Mrows (Bsz*Tsz)   // 32768

using f16x8 = __attribute__((ext_vector_type(8))) _Float16;
using f32x4 = __attribute__((ext_vector_type(4))) float;

typedef const __attribute__((address_space(1))) void* gas_ptr;
typedef __attribute__((address_space(3))) void* las_ptr;

__device__ inline float fast_sig(float x) { return 1.f / (1.f + __expf(-x)); }
__device__ inline float fast_tanh(float x) {
  const float e = __expf(-2.f * fabsf(x));
  const float y = (1.f - e) / (1.f + e);
  return x < 0.f ? -y : y;
}

// ---------------- fp32 -> fp16 convert ----------------
__global__ __launch_bounds__(256) void f32_to_f16(
    const float* __restrict__ src, _Float16* __restrict__ dst, int n8)
{
  const int idx = blockIdx.x * 256 + threadIdx.x;
  if (idx >= n8) return;
  const float4 v0 = *(const float4*)(src + (size_t)idx * 8);
  const float4 v1 = *(const float4*)(src + (size_t)idx * 8 + 4);
  _Float16 h[8];
  h[0] = (_Float16)v0.x; h[1] = (_Float16)v0.y;
  h[2] = (_Float16)v0.z; h[3] = (_Float16)v0.w;
  h[4] = (_Float16)v1.x; h[5] = (_Float16)v1.y;
  h[6] = (_Float16)v1.z; h[7] = (_Float16)v1.w;
  *(uint4*)(dst + (size_t)idx * 8) = *(uint4*)h;
}

// ---------------- fused GRU-layer GEMM, fp16 MFMA, async LDS staging ----------------
// Round-4 structure (32m x 64n wave tile, BK=32, 2 barriers/step, scalar-store
// epilogue). ONLY change: staging via global_load_lds width=16 (no VGPR
// round-trip). LDS: row-major A[128][32] fp16 at [0,4096), W[192][32] at
// [4096,10240) — lane-order contiguous as global_load_lds requires (no pad).
// grid: (M/128, 256/64, 3 cur). block 256 = 4 waves.
__global__ __launch_bounds__(256, 3) void gemm_gru_f16(
    const _Float16* __restrict__ Abase, size_t a_cur_stride,
    const _Float16* __restrict__ Wbase, size_t w_cur_stride,
    const float* __restrict__ bi_g, size_t bi_stride,
    const float* __restrict__ bh_g, size_t bh_stride,
    _Float16* __restrict__ Hout)
{
  __shared__ __attribute__((aligned(16))) _Float16 SB[10240];   // 20480 B

  const int tid = threadIdx.x;
  const int cu  = blockIdx.z;
  const int m0  = blockIdx.x * 128;
  const int n0  = blockIdx.y * 64;

  const _Float16* A = Abase + (size_t)cu * a_cur_stride;
  const _Float16* W = Wbase + (size_t)cu * w_cur_stride;
  const float* bi = bi_g + (size_t)cu * bi_stride;
  const float* bh = bh_g + (size_t)cu * bh_stride;

  const int lane = tid & 63;
  const int wv   = tid >> 6;
  const int q    = lane >> 4;      // k-chunk within frag
  const int c    = lane & 15;      // row/col within frag
  const int mb   = wv * 32;        // wave's row base within 128-tile

  // staging: lane covers (row = base + lane/4, chunk = lane&3) of 16B chunks
  const int sr  = lane >> 2;       // 0..15
  const int sch = lane & 3;        // 0..3

  // per-thread global element offsets (add k0 each step)
  const size_t ag0 = (size_t)(m0 + wv * 32 + sr) * 256 + sch * 8;
  const size_t ag1 = ag0 + (size_t)16 * 256;
  size_t wg[3]; int wlds[3];
  #pragma unroll
  for (int j = 0; j < 3; j++) {
    const int li  = wv * 3 + j;          // 0..11
    const int row = li * 16 + sr;        // 0..191
    const int s = row >> 6, rr = row & 63;
    wg[j]   = (size_t)(s * 256 + n0 + rr) * 256 + sch * 8;
    wlds[j] = 4096 + li * 512;           // fp16 units (1024 B per wave-load)
  }
  const int alds0 = (wv * 32) * 32;      // fp16 units
  const int alds1 = (wv * 32 + 16) * 32;

  f32x4 acc[3][2][4];
  #pragma unroll
  for (int s = 0; s < 3; s++)
    #pragma unroll
    for (int mi = 0; mi < 2; mi++)
      #pragma unroll
      for (int ni = 0; ni < 4; ni++)
        acc[s][mi][ni] = (f32x4)0.f;

  for (int k0 = 0; k0 < 256; k0 += 32) {
    // async global -> LDS staging (5 issues/thread, no VGPR round-trip)
    __builtin_amdgcn_global_load_lds((gas_ptr)(A + ag0 + k0),
                                     (las_ptr)(SB + alds0), 16, 0, 0);
    __builtin_amdgcn_global_load_lds((gas_ptr)(A + ag1 + k0),
                                     (las_ptr)(SB + alds1), 16, 0, 0);
    #pragma unroll
    for (int j = 0; j < 3; j++)
      __builtin_amdgcn_global_load_lds((gas_ptr)(W + wg[j] + k0),
                                       (las_ptr)(SB + wlds[j]), 16, 0, 0);
    __syncthreads();   // drains vmcnt -> staged data visible

    const f16x8 a0 = *(const f16x8*)&SB[(mb + c) * 32 + q * 8];
    const f16x8 a1 = *(const f16x8*)&SB[(mb + 16 + c) * 32 + q * 8];

    #pragma unroll
    for (int s = 0; s < 3; s++) {
      #pragma unroll
      for (int ni = 0; ni < 4; ni++) {
        const f16x8 w = *(const f16x8*)&SB[4096 + (s * 64 + ni * 16 + c) * 32 + q * 8];
        acc[s][0][ni] = __builtin_amdgcn_mfma_f32_16x16x32_f16(a0, w, acc[s][0][ni], 0, 0, 0);
        acc[s][1][ni] = __builtin_amdgcn_mfma_f32_16x16x32_f16(a1, w, acc[s][1][ni], 0, 0, 0);
      }
    }
    __syncthreads();   // all reads done before next overwrite
  }

  // ---- epilogue: gating (round-4 verbatim), h stored fp16 ----
  float bir[4], biz[4], bin_[4], bhr[4], bhz[4], bhn[4];
  #pragma unroll
  for (int ni = 0; ni < 4; ni++) {
    const int n = n0 + ni * 16 + c;
    bir[ni]  = bi[n];       bhr[ni] = bh[n];
    biz[ni]  = bi[256 + n]; bhz[ni] = bh[256 + n];
    bin_[ni] = bi[512 + n]; bhn[ni] = bh[512 + n];
  }
  #pragma unroll
  for (int mi = 0; mi < 2; mi++) {
    #pragma unroll
    for (int reg = 0; reg < 4; reg++) {
      const int m = m0 + mb + mi * 16 + q * 4 + reg;
      const size_t rowbase = ((size_t)cu * Mrows + m) * 256;
      #pragma unroll
      for (int ni = 0; ni < 4; ni++) {
        const float gr = acc[0][mi][ni][reg] + bir[ni] + bhr[ni];
        const float gz = acc[1][mi][ni][reg] + biz[ni] + bhz[ni];
        const float gn = acc[2][mi][ni][reg] + bin_[ni];
        const float r  = fast_sig(gr);
        const float zz = fast_sig(gz);
        const float nn = fast_tanh(gn + r * bhn[ni]);
        Hout[rowbase + n0 + ni * 16 + c] = (_Float16)((1.f - zz) * nn);
      }
    }
  }
}

// ---------------- per-layer dot products (e, p), block-tiled ----------------
__global__ __launch_bounds__(256) void ep_tile(
    const _Float16* __restrict__ Hh,
    const float* __restrict__ w_lw, const float* __restrict__ w_sel, int layer,
    float* __restrict__ e, float* __restrict__ p)
{
  __shared__ _Float16 hs[64 * 264];
  __shared__ float wc[7][256];
  __shared__ float ps[4][64][8];
  const int tid = threadIdx.x;
  const size_t mg0 = (size_t)blockIdx.x * 64;

  #pragma unroll
  for (int i = 0; i < 8; i++) {
    const int ci = tid + i * 256;
    const int row = ci >> 5, kc = ci & 31;
    *(uint4*)&hs[row * 264 + kc * 8] =
        *(const uint4*)(Hh + (mg0 + row) * 256 + kc * 8);
  }
  #pragma unroll
  for (int j = 0; j < 7; j++)
    wc[j][tid] = (j < 4) ? w_lw[j * 256 + tid] : w_sel[(j - 4) * 512 + tid];
  __syncthreads();

  const int r = tid & 63, pp = tid >> 6;
  float acc[7] = {0.f, 0.f, 0.f, 0.f, 0.f, 0.f, 0.f};
  #pragma unroll
  for (int i = 0; i < 8; i++) {
    union { uint4 u; _Float16 h[8]; } hvv;
    hvv.u = *(uint4*)&hs[r * 264 + pp * 64 + i * 8];
    float hf[8];
    #pragma unroll
    for (int k = 0; k < 8; k++) hf[k] = (float)hvv.h[k];
    #pragma unroll
    for (int j = 0; j < 7; j++) {
      const float4 w0 = *(const float4*)&wc[j][pp * 64 + i * 8];
      const float4 w1 = *(const float4*)&wc[j][pp * 64 + i * 8 + 4];
      acc[j] += hf[0] * w0.x + hf[1] * w0.y + hf[2] * w0.z + hf[3] * w0.w
              + hf[4] * w1.x + hf[5] * w1.y + hf[6] * w1.z + hf[7] * w1.w;
    }
  }
  #pragma unroll
  for (int j = 0; j < 7; j++) ps[pp][r][j] = acc[j];
  __syncthreads();

  if (tid < 64) {
    float d[7];
    #pragma unroll
    for (int j = 0; j < 7; j++)
      d[j] = ps[0][tid][j] + ps[1][tid][j] + ps[2][tid][j] + ps[3][tid][j];
    const size_t mg = mg0 + tid;
    const int cc = (int)(mg >> 15);
    const int m  = (int)(mg & 32767);
    const int b = m >> 8, t = m & 255;
    const size_t base = ((size_t)cc * Tsz + t) * Bsz + b;
    #pragma unroll
    for (int j = 0; j < 4; j++) e[base * 16 + layer * 4 + j] = d[j];
    #pragma unroll
    for (int j = 0; j < 3; j++) p[base * 12 + layer * 3 + j] = d[4 + j];
  }
}

// ---------------- softmax-attention + batch-reduced selector scores ----------------
__global__ __launch_bounds__(128) void attn_finish(
    const float* __restrict__ e, const float* __restrict__ p,
    const float* __restrict__ hidden, const float* __restrict__ b_lw,
    float* __restrict__ score_h)
{
  const int t = blockIdx.x, cc = blockIdx.y;
  const int b = threadIdx.x;
  const float* eb = e + ((size_t)(cc * Tsz + t) * Bsz + b) * 16;
  const float* pb = p + ((size_t)(cc * Tsz + t) * Bsz + b) * 12;
  const float* hb = hidden + b * 16;
  const float bl0 = b_lw[0], bl1 = b_lw[1], bl2 = b_lw[2], bl3 = b_lw[3];
  float attn[4];
  #pragma unroll
  for (int i = 0; i < 4; i++) {
    attn[i] = hb[i * 4 + 0] * (eb[i * 4 + 0] + bl0)
            + hb[i * 4 + 1] * (eb[i * 4 + 1] + bl1)
            + hb[i * 4 + 2] * (eb[i * 4 + 2] + bl2)
            + hb[i * 4 + 3] * (eb[i * 4 + 3] + bl3);
  }
  const float mx = fmaxf(fmaxf(attn[0], attn[1]), fmaxf(attn[2], attn[3]));
  float ex[4], sum = 0.f;
  #pragma unroll
  for (int i = 0; i < 4; i++) { ex[i] = expf(attn[i] - mx); sum += ex[i]; }
  const float inv = 1.f / sum;
  float sc[3];
  #pragma unroll
  for (int s = 0; s < 3; s++) {
    float v = 0.f;
    #pragma unroll
    for (int i = 0; i < 4; i++) v += ex[i] * pb[i * 3 + s];
    sc[s] = v * inv;
  }
  #pragma unroll
  for (int off = 32; off; off >>= 1)
    #pragma unroll
    for (int s = 0; s < 3; s++) sc[s] += __shfl_xor(sc[s], off);
  __shared__ float red[2][3];
  const int wv = threadIdx.x >> 6, ln = threadIdx.x & 63;
  if (ln == 0) { red[wv][0] = sc[0]; red[wv][1] = sc[1]; red[wv][2] = sc[2]; }
  __syncthreads();
  if (threadIdx.x == 0) {
    #pragma unroll
    for (int s = 0; s < 3; s++)
      score_h[((size_t)cc * Tsz + t) * 3 + s] = red[0][s] + red[1][s];
  }
}

// ---------------- xs[t,s] ----------------
__global__ __launch_bounds__(256) void xs_kernel(
    const float* __restrict__ x, const float* __restrict__ w_sel,
    const float* __restrict__ b_sel, float* __restrict__ xs)
{
  const int t = blockIdx.x, k = threadIdx.x;
  float s = 0.f;
  for (int b = 0; b < Bsz; b++) s += x[((size_t)b * Tsz + t) * Isz + k];
  float pr[3];
  #pragma unroll
  for (int qq = 0; qq < 3; qq++) pr[qq] = s * w_sel[qq * (Hsz + Isz) + Hsz + k];
  #pragma unroll
  for (int off = 32; off; off >>= 1)
    #pragma unroll
    for (int qq = 0; qq < 3; qq++) pr[qq] += __shfl_xor(pr[qq], off);
  __shared__ float red[4][3];
  const int wv = k >> 6, ln = k & 63;
  if (ln == 0) { red[wv][0] = pr[0]; red[wv][1] = pr[1]; red[wv][2] = pr[2]; }
  __syncthreads();
  if (k == 0) {
    #pragma unroll
    for (int qq = 0; qq < 3; qq++)
      xs[t * 3 + qq] = red[0][qq] + red[1][qq] + red[2][qq] + red[3][qq]
                      + (float)Bsz * b_sel[qq];
  }
}

// ---------------- selector chain via parallel scan ----------------
__global__ __launch_bounds__(256) void select_kernel(
    const float* __restrict__ score_h, const float* __restrict__ xs,
    int* __restrict__ cur)
{
  __shared__ unsigned char g[2][Tsz][3];
  const int t = threadIdx.x;
  if (t == 0) {
    g[0][0][0] = 0; g[0][0][1] = 1; g[0][0][2] = 2;
  } else {
    const float* xr = xs + t * 3;
    #pragma unroll
    for (int cc = 0; cc < 3; cc++) {
      const float* sh = score_h + ((size_t)cc * Tsz + (t - 1)) * 3;
      const float v0 = sh[0] + xr[0];
      const float v1 = sh[1] + xr[1];
      const float v2 = sh[2] + xr[2];
      int best = 0; float bv = v0;
      if (v1 > bv) { bv = v1; best = 1; }
      if (v2 > bv) { bv = v2; best = 2; }
      g[0][t][cc] = (unsigned char)best;
    }
  }
  __syncthreads();
  int src = 0;
  for (int off = 1; off < Tsz; off <<= 1) {
    const int dst = src ^ 1;
    if (t >= off) {
      #pragma unroll
      for (int s = 0; s < 3; s++)
        g[dst][t][s] = g[src][t][g[src][t - off][s]];
    } else {
      #pragma unroll
      for (int s = 0; s < 3; s++) g[dst][t][s] = g[src][t][s];
    }
    __syncthreads();
    src = dst;
  }
  cur[t] = (int)g[src][t][0];
}

// ---------------- gather outputs (fp16 h -> fp32 out) ----------------
__global__ __launch_bounds__(256) void gather_out(
    const _Float16* __restrict__ Hh, const int* __restrict__ cur,
    float* __restrict__ out)
{
  const size_t idx = ((size_t)blockIdx.x * 256 + threadIdx.x) * 4;
  const size_t BTH = (size_t)Bsz * Tsz * Hsz;
  int b, t, h;
  if (idx < BTH) {
    b = (int)(idx >> 16);
    const int rem = (int)(idx & 65535);
    t = rem >> 8; h = rem & 255;
  } else {
    const size_t r2 = idx - BTH;
    b = (int)(r2 >> 8); h = (int)(r2 & 255); t = Tsz - 1;
  }
  const int cc = cur[t];
  const size_t g = (((size_t)cc * Mrows + (size_t)b * Tsz + t) * Hsz + h);
  union { ushort4 u; _Float16 hv[4]; } cv;
  cv.u = *(const ushort4*)(Hh + g);
  float4 v;
  v.x = (float)cv.hv[0]; v.y = (float)cv.hv[1];
  v.z = (float)cv.hv[2]; v.w = (float)cv.hv[3];
  *(float4*)(out + idx) = v;
}

extern "C" void kernel_launch(void* const* d_in, const int* in_sizes, int n_in,
                              void* d_out, int out_size, void* d_ws, size_t ws_size,
                              hipStream_t stream) {
  const float* x      = (const float*)d_in[0];
  const float* hidden = (const float*)d_in[1];
  const float* w_ih0  = (const float*)d_in[2];
  const float* b_ih0  = (const float*)d_in[3];
  const float* b_hh0  = (const float*)d_in[4];
  const float* w_ih   = (const float*)d_in[5];
  const float* b_ih   = (const float*)d_in[6];
  const float* b_hh   = (const float*)d_in[7];
  const float* w_lw   = (const float*)d_in[8];
  const float* b_lw   = (const float*)d_in[9];
  const float* w_sel  = (const float*)d_in[10];
  const float* b_sel  = (const float*)d_in[11];
  float* out = (float*)d_out;

  char* w = (char*)d_ws;
  const size_t HN = (size_t)3 * Mrows * 256;       // 25.2M
  const size_t XN = (size_t)Bsz * Tsz * Isz;       // 8.39M
  const size_t W0N = (size_t)3 * 768 * 256;        // 589824
  const size_t WLN = (size_t)3 * 3 * 768 * 256;    // 1769472
  _Float16* HA  = (_Float16*)w; w += HN * 2;
  _Float16* HB  = (_Float16*)w; w += HN * 2;
  _Float16* xh  = (_Float16*)w; w += XN * 2;
  _Float16* Wh0 = (_Float16*)w; w += W0N * 2;
  _Float16* WhL = (_Float16*)w; w += WLN * 2;
  float* e       = (float*)w; w += (size_t)3 * Tsz * Bsz * 16 * 4;
  float* p       = (float*)w; w += (size_t)3 * Tsz * Bsz * 12 * 4;
  float* score_h = (float*)w; w += (size_t)3 * Tsz * 3 * 4;
  float* xsb     = (float*)w; w += (size_t)Tsz * 3 * 4;
  int*   curb    = (int*)w;   w += (size_t)Tsz * 4;

  // fp32 -> fp16 conversions
  f32_to_f16<<<(int)(XN / 8 + 255) / 256, 256, 0, stream>>>(x, xh, (int)(XN / 8));
  f32_to_f16<<<(int)(W0N / 8 + 255) / 256, 256, 0, stream>>>(w_ih0, Wh0, (int)(W0N / 8));
  f32_to_f16<<<(int)(WLN / 8 + 255) / 256, 256, 0, stream>>>(w_ih, WhL, (int)(WLN / 8));

  dim3 ggrid(Mrows / 128, 4, 3);

  // layer 0: A = xh (shared across cur)
  gemm_gru_f16<<<ggrid, 256, 0, stream>>>(
      xh, (size_t)0, Wh0, (size_t)768 * 256,
      b_ih0, (size_t)768, b_hh0, (size_t)768, HA);
  ep_tile<<<(3 * Mrows) / 64, 256, 0, stream>>>(HA, w_lw, w_sel, 0, e, p);

  const size_t wcur = (size_t)3 * 768 * 256;
  const size_t bst  = (size_t)3 * 768;
  _Float16* ping = HA; _Float16* pong = HB;
  for (int l = 1; l < 4; l++) {
    gemm_gru_f16<<<ggrid, 256, 0, stream>>>(
        ping, (size_t)Mrows * 256,
        WhL + (size_t)(l - 1) * 768 * 256, wcur,
        b_ih + (size_t)(l - 1) * 768, bst,
        b_hh + (size_t)(l - 1) * 768, bst, pong);
    ep_tile<<<(3 * Mrows) / 64, 256, 0, stream>>>(pong, w_lw, w_sel, l, e, p);
    _Float16* t1 = ping; ping = pong; pong = t1;
  }

  attn_finish<<<dim3(Tsz, 3), 128, 0, stream>>>(e, p, hidden, b_lw, score_h);
  xs_kernel<<<Tsz, 256, 0, stream>>>(x, w_sel, b_sel, xsb);
  select_kernel<<<1, 256, 0, stream>>>(score_h, xsb, curb);
  gather_out<<<8224, 256, 0, stream>>>(ping, curb, out);
}